// Round 11
// baseline (166.958 us; speedup 1.0000x reference)
//
#include <hip/hip_runtime.h>
#include <hip/hip_cooperative_groups.h>
#include <math.h>

namespace cg = cooperative_groups;

// DigitCaps2: B=128, C=1024 in_caps, I=16 in_dim, N=16 num_caps, D=16 dim_caps
#define NB 128
#define NC 1024
#define NN 16
#define ND 16
#define NI 16
#define COEF 0.25f

typedef __attribute__((ext_vector_type(8))) short short8;
typedef __attribute__((ext_vector_type(4))) float f32x4;
typedef unsigned short ushort_t;

__device__ __forceinline__ unsigned short f2bf(float f) {
  unsigned int u = __builtin_bit_cast(unsigned int, f);
  u += 0x7fffu + ((u >> 16) & 1u);
  return (unsigned short)(u >> 16);
}
__device__ __forceinline__ short8 cvt8(float4 a, float4 b) {
  short8 o;
  o[0] = (short)f2bf(a.x); o[1] = (short)f2bf(a.y);
  o[2] = (short)f2bf(a.z); o[3] = (short)f2bf(a.w);
  o[4] = (short)f2bf(b.x); o[5] = (short)f2bf(b.y);
  o[6] = (short)f2bf(b.z); o[7] = (short)f2bf(b.w);
  return o;
}

// ============ cooperative single kernel ============
// 256 blocks x 1024 threads. blk = btg*128 + cc: btg owns b in [btg*64,+64),
// cc owns c in [cc*8,+8). W slice staged bf16 in LDS ONCE, reused in all phases.
// upart: [128 rows (n*8+bt16)][128 cc][256 (b16*16+d)]; usum: [16][128][16].
__global__ __launch_bounds__(1024) void k_all(const float* __restrict__ xf,
                                              const float* __restrict__ Wf,
                                              const float* __restrict__ Bbias,
                                              float* __restrict__ out,
                                              float* __restrict__ upart,
                                              float* __restrict__ usum) {
  __shared__ ushort_t Wl[NN][8][ND][NI];  // 64 KB  [n][c][d][i]
  __shared__ ushort_t xl[64][136];        // 17.4 KB [b_local][c*16+i] padded
  __shared__ float scl[NN][8][64];        // 32 KB  [n][c][b_local]
  __shared__ float red2[8][132];          // 4.2 KB phase2/6 cross-wave reduce

  cg::grid_group grid = cg::this_grid();
  const int blk = blockIdx.x;
  const int btg = blk >> 7, cc = blk & 127;
  const int t = threadIdx.x;
  const int w = t >> 6, l = t & 63;
  const int q = l >> 4, b16 = l & 15;
  const int c0 = cc * 8;
  const int n = w;  // wave owns one n

  // ---- phase 1a: stage W slice (f32 -> bf16), 4096 groups of 8 floats ----
  {
    ushort_t* Wflat = &Wl[0][0][0][0];
#pragma unroll
    for (int r = 0; r < 4; ++r) {
      int f = r * 1024 + t;
      int nn = f >> 8, rem = f & 255;  // per-n slice is 2048 contiguous floats
      const float* src = Wf + ((size_t)(nn * NC + c0)) * 256 + rem * 8;
      float4 a = *(const float4*)src;
      float4 b = *(const float4*)(src + 4);
      *(short8*)(Wflat + nn * 2048 + rem * 8) = cvt8(a, b);
    }
    // stage x: 64 rows x 128 floats
    int row = t >> 4, rem = t & 15;
    const float* src = xf + ((size_t)(btg * 64 + row) * NC + c0) * 16 + rem * 8;
    float4 a = *(const float4*)src;
    float4 b = *(const float4*)(src + 4);
    *(short8*)(&xl[row][rem * 8]) = cvt8(a, b);
  }
  __syncthreads();

  // ---- phase 1b: usum partials. wave n, 4 b16-tiles, K=128 over (8c x 16i) ----
#pragma unroll
  for (int g2 = 0; g2 < 4; ++g2) {
    f32x4 acc = {0.f, 0.f, 0.f, 0.f};
#pragma unroll
    for (int kk = 0; kk < 4; ++kk) {
      short8 av = *(const short8*)(&Wl[n][kk * 2 + (q >> 1)][b16][(q & 1) * 8]);
      short8 bv = *(const short8*)(&xl[g2 * 16 + b16][(kk * 2 + (q >> 1)) * 16 + (q & 1) * 8]);
      acc = __builtin_amdgcn_mfma_f32_16x16x32_bf16(av, bv, acc, 0, 0, 0);
    }
    int row = n * 8 + btg * 4 + g2;
    *(f32x4*)(upart + ((size_t)row * 128 + cc) * 256 + b16 * 16 + q * 4) = acc;
  }
  grid.sync();

  // ---- phase 2: reduce upart over 128 cc -> usum[n][b][d] ----
  {
    int row = blk >> 1;
    int ph = (blk & 1) * 128;
    int j = t >> 7, ol = t & 127;
    const float* pp = upart + ((size_t)row * 128 + j * 16) * 256 + ph + ol;
    float s = 0.f;
#pragma unroll
    for (int s16 = 0; s16 < 16; ++s16) { s += *pp; pp += 256; }
    red2[j][ol] = s;
    __syncthreads();
    if (t < 128) {
      float tot = 0.f;
#pragma unroll
      for (int jj = 0; jj < 8; ++jj) tot += red2[jj][t];
      int pos = ph + t;
      int nn = row >> 3, bt16 = row & 7;
      int b = bt16 * 16 + (pos >> 4), d = pos & 15;
      usum[((size_t)nn * NB + b) * ND + d] = tot;
    }
  }
  grid.sync();

  // ---- phase 3: scores -> scl[n][c][b_local] ----
  {
    f32x4 us[4];
#pragma unroll
    for (int g2 = 0; g2 < 4; ++g2)
      us[g2] = *(const f32x4*)(usum + ((size_t)n * NB + btg * 64 + g2 * 16 + b16) * ND + q * 4);
#pragma unroll
    for (int c = 0; c < 8; ++c) {
#pragma unroll
      for (int g2 = 0; g2 < 4; ++g2) {
        short8 av = {0, 0, 0, 0, 0, 0, 0, 0};
        short8 bv = {0, 0, 0, 0, 0, 0, 0, 0};
        if (q < 2) {
          av = *(const short8*)(&Wl[n][c][b16][q * 8]);
          bv = *(const short8*)(&xl[g2 * 16 + b16][c * 16 + q * 8]);
        }
        f32x4 z = {0.f, 0.f, 0.f, 0.f};
        f32x4 d = __builtin_amdgcn_mfma_f32_16x16x32_bf16(av, bv, z, 0, 0, 0);
        float v = us[g2][0] * d[0] + us[g2][1] * d[1] + us[g2][2] * d[2] + us[g2][3] * d[3];
        v += __shfl_xor(v, 16);
        v += __shfl_xor(v, 32);
        if (l < 16) scl[n][c][g2 * 16 + l] = COEF * v;
      }
    }
  }
  __syncthreads();

  // ---- phase 4: softmax over n + bias (512 threads own (c, b_local)) ----
  if (t < 512) {
    int c = t >> 6, b = t & 63;
    float v[NN];
    float m = -1e30f;
#pragma unroll
    for (int k = 0; k < NN; ++k) {
      v[k] = scl[k][c][b];
      m = fmaxf(m, v[k]);
    }
    float sum = 0.f;
#pragma unroll
    for (int k = 0; k < NN; ++k) {
      v[k] = expf(v[k] - m);
      sum += v[k];
    }
    float inv = 1.0f / sum;
#pragma unroll
    for (int k = 0; k < NN; ++k) scl[k][c][b] = v[k] * inv + Bbias[k * NC + c0 + c];
  }
  __syncthreads();

  // ---- phase 5: weighted sum (recompute d-tiles from LDS) -> spart (= upart) ----
  {
    f32x4 acc[4];
#pragma unroll
    for (int g2 = 0; g2 < 4; ++g2) acc[g2] = (f32x4){0.f, 0.f, 0.f, 0.f};
#pragma unroll
    for (int c = 0; c < 8; ++c) {
#pragma unroll
      for (int g2 = 0; g2 < 4; ++g2) {
        short8 av = {0, 0, 0, 0, 0, 0, 0, 0};
        short8 bv = {0, 0, 0, 0, 0, 0, 0, 0};
        if (q < 2) {
          av = *(const short8*)(&Wl[n][c][b16][q * 8]);
          bv = *(const short8*)(&xl[g2 * 16 + b16][c * 16 + q * 8]);
        }
        f32x4 z = {0.f, 0.f, 0.f, 0.f};
        f32x4 d = __builtin_amdgcn_mfma_f32_16x16x32_bf16(av, bv, z, 0, 0, 0);
        float cf = scl[n][c][g2 * 16 + b16];
        acc[g2][0] = fmaf(cf, d[0], acc[g2][0]);
        acc[g2][1] = fmaf(cf, d[1], acc[g2][1]);
        acc[g2][2] = fmaf(cf, d[2], acc[g2][2]);
        acc[g2][3] = fmaf(cf, d[3], acc[g2][3]);
      }
    }
#pragma unroll
    for (int g2 = 0; g2 < 4; ++g2) {
      int row = n * 8 + btg * 4 + g2;
      *(f32x4*)(upart + ((size_t)row * 128 + cc) * 256 + b16 * 16 + q * 4) = acc[g2];
    }
  }
  grid.sync();

  // ---- phase 6: reduce spart over cc + squash -> out[b][n][d] ----
  {
    int row = blk >> 1;
    int ph = (blk & 1) * 128;
    int j = t >> 7, ol = t & 127;
    const float* pp = upart + ((size_t)row * 128 + j * 16) * 256 + ph + ol;
    float s = 0.f;
#pragma unroll
    for (int s16 = 0; s16 < 16; ++s16) { s += *pp; pp += 256; }
    __syncthreads();  // red2 free (phase 2 done grid-wide)
    red2[j][ol] = s;
    __syncthreads();
    if (t < 128) {
      float sv = 0.f;
#pragma unroll
      for (int jj = 0; jj < 8; ++jj) sv += red2[jj][t];
      float sq = sv * sv;
      sq += __shfl_xor(sq, 1);
      sq += __shfl_xor(sq, 2);
      sq += __shfl_xor(sq, 4);
      sq += __shfl_xor(sq, 8);  // sum over d (t&15 group)
      float norm = sqrtf(sq);
      float scale = (1.0f - expf(-norm)) / sqrtf(sq + 1e-8f);
      int pos = ph + t;
      int nn = row >> 3, bt16 = row & 7;
      int b = bt16 * 16 + (pos >> 4), d = pos & 15;
      out[((size_t)b * NN + nn) * ND + d] = sv * scale;
    }
  }
}

// ============ fallback: exact r9 4-kernel pipeline ============
__global__ __launch_bounds__(256) void k_prep(const float4* __restrict__ x,
                                              const float4* __restrict__ W,
                                              ushort_t* __restrict__ xb,
                                              ushort_t* __restrict__ Wb) {
  int id = blockIdx.x * 256 + threadIdx.x;
  const float4* src;
  ushort_t* dst;
  int k;
  if (id < 262144) { src = x; dst = xb; k = id; }
  else { src = W; dst = Wb; k = id - 262144; }
  float4 a = src[2 * k], b = src[2 * k + 1];
  *(short8*)(dst + (size_t)k * 8) = cvt8(a, b);
}

__global__ __launch_bounds__(1024) void k_usum(const ushort_t* __restrict__ xb,
                                               const ushort_t* __restrict__ Wb,
                                               float* __restrict__ usum2) {
  __shared__ f32x4 red[16][64];
  int bx = blockIdx.x;
  int bt = bx >> 5, g = bx & 31;
  int n = g >> 1, h = g & 1;
  int w = threadIdx.x >> 6, l = threadIdx.x & 63;
  int q = l >> 4, b16 = l & 15;
  int c0 = h * 512 + w * 32;
  f32x4 acc[4];
#pragma unroll
  for (int kk = 0; kk < 4; ++kk) acc[kk] = (f32x4){0.f, 0.f, 0.f, 0.f};
#pragma unroll
  for (int kk = 0; kk < 4; ++kk) {
    const ushort_t* ap =
        Wb + (((size_t)(n * NC + c0 + kk * 8 + (q >> 1)) * ND + b16) * NI) + (q & 1) * 8;
    const ushort_t* bp =
        xb + (size_t)(bt * 16 + b16) * (NC * NI) + (c0 + kk * 8 + (q >> 1)) * NI + (q & 1) * 8;
#pragma unroll
    for (int s = 0; s < 4; ++s) {
      short8 av = *(const short8*)ap;
      short8 bv = *(const short8*)bp;
      acc[kk] = __builtin_amdgcn_mfma_f32_16x16x32_bf16(av, bv, acc[kk], 0, 0, 0);
      ap += 2 * ND * NI;
      bp += 2 * NI;
    }
  }
  red[w][l] = (acc[0] + acc[1]) + (acc[2] + acc[3]);
  __syncthreads();
  if (threadIdx.x < 64) {
    f32x4 tt = red[0][l];
#pragma unroll
    for (int k = 1; k < 16; ++k) tt += red[k][l];
    *(f32x4*)(usum2 + (((size_t)h * NN + n) * NB + bt * 16 + b16) * ND + q * 4) = tt;
  }
}

__global__ __launch_bounds__(512, 4) void k_bc(const ushort_t* __restrict__ xb,
                                               const ushort_t* __restrict__ Wb,
                                               const float* __restrict__ usum2,
                                               const float* __restrict__ Bbias,
                                               float* __restrict__ part) {
  __shared__ ushort_t Wl[NN][8][ND][NI];
  __shared__ ushort_t xl[16][136];
  __shared__ float scl[NN][8][16];
  int bx = blockIdx.x;
  int bt = bx >> 7, cc = bx & 127;
  int t = threadIdx.x;
  int w = t >> 6, l = t & 63;
  int q = l >> 4, b16 = l & 15;
  int c0 = cc * 8;
  int n0 = w, n1 = w + 8;
  const float* u0p = usum2 + ((size_t)n0 * NB + bt * 16 + b16) * ND + q * 4;
  f32x4 us0 = *(const f32x4*)u0p + *(const f32x4*)(u0p + (size_t)NN * NB * ND);
  const float* u1p = usum2 + ((size_t)n1 * NB + bt * 16 + b16) * ND + q * 4;
  f32x4 us1 = *(const f32x4*)u1p + *(const f32x4*)(u1p + (size_t)NN * NB * ND);
  {
    ushort_t* Wflat = &Wl[0][0][0][0];
    const ushort_t* Wsrc = Wb + (size_t)c0 * (ND * NI);
#pragma unroll
    for (int r = 0; r < 8; ++r) {
      int g = r * 512 + t;
      int nn = g >> 8, rem = g & 255;
      *(short8*)(Wflat + nn * 2048 + rem * 8) =
          *(const short8*)(Wsrc + (size_t)nn * (NC * ND * NI) + rem * 8);
    }
    if (t < 256) {
      int b = t >> 4, j = t & 15;
      int c = j >> 1, i8 = j & 1;
      *(short8*)(&xl[b][c * 16 + i8 * 8]) =
          *(const short8*)(xb + ((size_t)(bt * 16 + b) * NC + c0 + c) * NI + i8 * 8);
    }
  }
  __syncthreads();
  f32x4 t0[8], t1[8];
#pragma unroll
  for (int c = 0; c < 8; ++c) {
    short8 av = {0, 0, 0, 0, 0, 0, 0, 0};
    short8 bv = {0, 0, 0, 0, 0, 0, 0, 0};
    if (q < 2) {
      av = *(const short8*)(&Wl[n0][c][b16][q * 8]);
      bv = *(const short8*)(&xl[b16][c * 16 + q * 8]);
    }
    f32x4 z = {0.f, 0.f, 0.f, 0.f};
    f32x4 d = __builtin_amdgcn_mfma_f32_16x16x32_bf16(av, bv, z, 0, 0, 0);
    t0[c] = d;
    float v = us0[0] * d[0] + us0[1] * d[1] + us0[2] * d[2] + us0[3] * d[3];
    v += __shfl_xor(v, 16);
    v += __shfl_xor(v, 32);
    if (l < 16) scl[n0][c][l] = COEF * v;
  }
#pragma unroll
  for (int c = 0; c < 8; ++c) {
    short8 av = {0, 0, 0, 0, 0, 0, 0, 0};
    short8 bv = {0, 0, 0, 0, 0, 0, 0, 0};
    if (q < 2) {
      av = *(const short8*)(&Wl[n1][c][b16][q * 8]);
      bv = *(const short8*)(&xl[b16][c * 16 + q * 8]);
    }
    f32x4 z = {0.f, 0.f, 0.f, 0.f};
    f32x4 d = __builtin_amdgcn_mfma_f32_16x16x32_bf16(av, bv, z, 0, 0, 0);
    t1[c] = d;
    float v = us1[0] * d[0] + us1[1] * d[1] + us1[2] * d[2] + us1[3] * d[3];
    v += __shfl_xor(v, 16);
    v += __shfl_xor(v, 32);
    if (l < 16) scl[n1][c][l] = COEF * v;
  }
  __syncthreads();
  if (t < 128) {
    int c = t >> 4, b = t & 15;
    float v[NN];
    float m = -1e30f;
#pragma unroll
    for (int k = 0; k < NN; ++k) {
      v[k] = scl[k][c][b];
      m = fmaxf(m, v[k]);
    }
    float sum = 0.f;
#pragma unroll
    for (int k = 0; k < NN; ++k) {
      v[k] = expf(v[k] - m);
      sum += v[k];
    }
    float inv = 1.0f / sum;
#pragma unroll
    for (int k = 0; k < NN; ++k) scl[k][c][b] = v[k] * inv + Bbias[k * NC + c0 + c];
  }
  __syncthreads();
  f32x4 acc0 = {0.f, 0.f, 0.f, 0.f};
  f32x4 acc1 = {0.f, 0.f, 0.f, 0.f};
#pragma unroll
  for (int c = 0; c < 8; ++c) {
    float cf0 = scl[n0][c][b16];
    float cf1 = scl[n1][c][b16];
    acc0[0] = fmaf(cf0, t0[c][0], acc0[0]);
    acc0[1] = fmaf(cf0, t0[c][1], acc0[1]);
    acc0[2] = fmaf(cf0, t0[c][2], acc0[2]);
    acc0[3] = fmaf(cf0, t0[c][3], acc0[3]);
    acc1[0] = fmaf(cf1, t1[c][0], acc1[0]);
    acc1[1] = fmaf(cf1, t1[c][1], acc1[1]);
    acc1[2] = fmaf(cf1, t1[c][2], acc1[2]);
    acc1[3] = fmaf(cf1, t1[c][3], acc1[3]);
  }
  *(f32x4*)(part + ((size_t)((n0 * 8 + bt) * 128 + cc)) * 256 + b16 * 16 + q * 4) = acc0;
  *(f32x4*)(part + ((size_t)((n1 * 8 + bt) * 128 + cc)) * 256 + b16 * 16 + q * 4) = acc1;
}

__global__ __launch_bounds__(256) void k_fin(const float* __restrict__ part,
                                             float* __restrict__ out) {
  int id2 = blockIdx.x * 256 + threadIdx.x;
  int h = id2 & 1;
  int id = id2 >> 1;
  int dq = id & 3, n = (id >> 2) & 15, b = id >> 6;
  int bt = b >> 4, b16 = b & 15;
  f32x4 sv = {0.f, 0.f, 0.f, 0.f};
  const float* pp = part + ((size_t)((n * 8 + bt) * 128 + h * 64)) * 256 + b16 * 16 + dq * 4;
  for (int k = 0; k < 64; ++k) {
    sv += *(const f32x4*)pp;
    pp += 256;
  }
  sv[0] += __shfl_xor(sv[0], 1);
  sv[1] += __shfl_xor(sv[1], 1);
  sv[2] += __shfl_xor(sv[2], 1);
  sv[3] += __shfl_xor(sv[3], 1);
  float sq = sv[0] * sv[0] + sv[1] * sv[1] + sv[2] * sv[2] + sv[3] * sv[3];
  sq += __shfl_xor(sq, 2);
  sq += __shfl_xor(sq, 4);
  float norm = sqrtf(sq);
  float scale = (1.0f - expf(-norm)) / sqrtf(sq + 1e-8f);
  if (h == 0) {
    f32x4 o = {sv[0] * scale, sv[1] * scale, sv[2] * scale, sv[3] * scale};
    *(f32x4*)(out + (size_t)id * 4) = o;
  }
}

extern "C" void kernel_launch(void* const* d_in, const int* in_sizes, int n_in,
                              void* d_out, int out_size, void* d_ws, size_t ws_size,
                              hipStream_t stream) {
  const float* x = (const float*)d_in[0];   // [128][1024][16]
  const float* W = (const float*)d_in[1];   // [1][16][1024][16][16]
  const float* Bb = (const float*)d_in[2];  // [16][1][1024]
  float* out = (float*)d_out;               // [128][16][16]
  float* ws = (float*)d_ws;

  // cooperative path buffers
  float* upart = ws;                 // [128][128][256] = 4,194,304 f
  float* usum = ws + 4194304;        // 32,768 f
  // fallback (r9) buffers, disjoint region
  float* fb = ws + 4227072;
  ushort_t* xb = (ushort_t*)fb;                  // 1,048,576 f
  ushort_t* Wb = (ushort_t*)(fb + 1048576);      // 2,097,152 f
  float* part = fb + 1048576 + 2097152;          // 4,194,304 f
  float* usum2 = part + 4194304;                 // 65,536 f

  void* args[] = {(void*)&x, (void*)&W, (void*)&Bb, (void*)&out,
                  (void*)&upart, (void*)&usum};
  hipError_t e = hipLaunchCooperativeKernel((const void*)k_all, dim3(256), dim3(1024),
                                            args, 0, stream);
  if (e != hipSuccess) {
    // r9 pipeline fallback (deterministic: triggers consistently if coop unsupported)
    hipLaunchKernelGGL(k_prep, dim3(3072), dim3(256), 0, stream,
                       (const float4*)x, (const float4*)W, xb, Wb);
    hipLaunchKernelGGL(k_usum, dim3(256), dim3(1024), 0, stream, xb, Wb, usum2);
    hipLaunchKernelGGL(k_bc, dim3(1024), dim3(512), 0, stream, xb, Wb, usum2, Bb, part);
    hipLaunchKernelGGL(k_fin, dim3(64), dim3(256), 0, stream, part, out);
  }
}

// Round 12
// 51.563 us; speedup vs baseline: 3.2379x; 3.2379x over previous
//
#include <hip/hip_runtime.h>
#include <math.h>

// DigitCaps2: B=128, C=1024 in_caps, I=16 in_dim, N=16 num_caps, D=16 dim_caps
#define NB 128
#define NC 1024
#define NN 16
#define ND 16
#define NI 16
#define COEF 0.25f

typedef __attribute__((ext_vector_type(8))) short short8;
typedef __attribute__((ext_vector_type(4))) float f32x4;
typedef unsigned short ushort_t;

__device__ __forceinline__ unsigned short f2bf(float f) {
  unsigned int u = __builtin_bit_cast(unsigned int, f);
  u += 0x7fffu + ((u >> 16) & 1u);
  return (unsigned short)(u >> 16);
}
__device__ __forceinline__ short8 cvt8(float4 a, float4 b) {
  short8 o;
  o[0] = (short)f2bf(a.x); o[1] = (short)f2bf(a.y);
  o[2] = (short)f2bf(a.z); o[3] = (short)f2bf(a.w);
  o[4] = (short)f2bf(b.x); o[5] = (short)f2bf(b.y);
  o[6] = (short)f2bf(b.z); o[7] = (short)f2bf(b.w);
  return o;
}

// K1: convert x only (262144 groups of 8 floats).
__global__ __launch_bounds__(256) void k_prepx(const float4* __restrict__ x,
                                               ushort_t* __restrict__ xb) {
  int id = blockIdx.x * 256 + threadIdx.x;
  float4 a = x[2 * id], b = x[2 * id + 1];
  *(short8*)(xb + (size_t)id * 8) = cvt8(a, b);
}

// K2: usum half-partials; W read f32 (converted in-register), bt==0 stores bf16 W.
// bx = bt*32 + (n*2+h): the 8 bt-blocks sharing a W half-slice share an XCD, so
// the f32 W re-reads are L2 hits (512 KB half-slice << 4 MB L2). x read as bf16.
// 16 waves; wave w owns c in [h*512 + w*32, +32) as 4 independent 4-step chains.
__global__ __launch_bounds__(1024) void k_usum(const ushort_t* __restrict__ xb,
                                               const float* __restrict__ Wf,
                                               ushort_t* __restrict__ Wb,
                                               float* __restrict__ usum2) {
  __shared__ f32x4 red[16][64];  // 16 KB
  int bx = blockIdx.x;
  int bt = bx >> 5, g = bx & 31;
  int n = g >> 1, h = g & 1;
  int w = threadIdx.x >> 6, l = threadIdx.x & 63;
  int q = l >> 4, b16 = l & 15;
  int c0 = h * 512 + w * 32;
  const bool writeW = (bt == 0);
  f32x4 acc[4];
#pragma unroll
  for (int kk = 0; kk < 4; ++kk) acc[kk] = (f32x4){0.f, 0.f, 0.f, 0.f};
#pragma unroll
  for (int kk = 0; kk < 4; ++kk) {
    size_t wo = (((size_t)(n * NC + c0 + kk * 8 + (q >> 1)) * ND + b16) * NI) + (q & 1) * 8;
    const ushort_t* bp =
        xb + (size_t)(bt * 16 + b16) * (NC * NI) + (c0 + kk * 8 + (q >> 1)) * NI + (q & 1) * 8;
#pragma unroll
    for (int s = 0; s < 4; ++s) {
      float4 w0 = *(const float4*)(Wf + wo);
      float4 w1 = *(const float4*)(Wf + wo + 4);
      short8 av = cvt8(w0, w1);
      if (writeW) *(short8*)(Wb + wo) = av;
      short8 bv = *(const short8*)bp;
      acc[kk] = __builtin_amdgcn_mfma_f32_16x16x32_bf16(av, bv, acc[kk], 0, 0, 0);
      wo += 2 * ND * NI;
      bp += 2 * NI;
    }
  }
  red[w][l] = (acc[0] + acc[1]) + (acc[2] + acc[3]);
  __syncthreads();
  if (threadIdx.x < 64) {
    f32x4 t = red[0][l];
#pragma unroll
    for (int k = 1; k < 16; ++k) t += red[k][l];
    *(f32x4*)(usum2 + (((size_t)h * NN + n) * NB + bt * 16 + b16) * ND + q * 4) = t;
  }
}

// K3: fused scores + softmax + weighted-sum. LDS-staged W/x, register u_hat tiles.
// grid = 1024 blocks (bt = bx>>7, cc = bx&127); blocks sharing cc share an XCD
// (bx mod 8 = cc mod 8) so the W slice is fetched from HBM once per XCD.
// 512 threads = 8 waves; wave w handles n = w and n = w+8.
__global__ __launch_bounds__(512, 4) void k_bc(const ushort_t* __restrict__ xb,
                                               const ushort_t* __restrict__ Wb,
                                               const float* __restrict__ usum2,
                                               const float* __restrict__ Bbias,
                                               float* __restrict__ part) {
  __shared__ ushort_t Wl[NN][8][ND][NI];  // 64 KB, [n][c][d][i]
  __shared__ ushort_t xl[16][136];        // x tile [b][c*16+i], padded stride
  __shared__ float scl[NN][8][16];        // 8 KB, [n][c][b16]
  int bx = blockIdx.x;
  int bt = bx >> 7, cc = bx & 127;
  int t = threadIdx.x;
  int w = t >> 6, l = t & 63;
  int q = l >> 4, b16 = l & 15;
  int c0 = cc * 8;
  int n0 = w, n1 = w + 8;

  // usum loads issued first so they overlap the staging burst below
  const float* u0p = usum2 + ((size_t)n0 * NB + bt * 16 + b16) * ND + q * 4;
  f32x4 us0 = *(const f32x4*)u0p + *(const f32x4*)(u0p + (size_t)NN * NB * ND);
  const float* u1p = usum2 + ((size_t)n1 * NB + bt * 16 + b16) * ND + q * 4;
  f32x4 us1 = *(const f32x4*)u1p + *(const f32x4*)(u1p + (size_t)NN * NB * ND);

  // ---- stage W slice: 16 n x (8 c x 256) shorts = 4096 short8 groups ----
  {
    ushort_t* Wflat = &Wl[0][0][0][0];
    const ushort_t* Wsrc = Wb + (size_t)c0 * (ND * NI);
#pragma unroll
    for (int r = 0; r < 8; ++r) {
      int g = r * 512 + t;            // 0..4095
      int n = g >> 8, rem = g & 255;  // 256 short8 per n-chunk (contiguous)
      *(short8*)(Wflat + n * 2048 + rem * 8) =
          *(const short8*)(Wsrc + (size_t)n * (NC * ND * NI) + rem * 8);
    }
    // stage x slice: 16 b x 8 c x 16 i
    if (t < 256) {
      int b = t >> 4, j = t & 15;  // j = c*2 + i-half
      int c = j >> 1, i8 = j & 1;
      *(short8*)(&xl[b][c * 16 + i8 * 8]) =
          *(const short8*)(xb + ((size_t)(bt * 16 + b) * NC + c0 + c) * NI + i8 * 8);
    }
  }
  __syncthreads();

  f32x4 t0[8], t1[8];  // u_hat d-tiles, kept in registers across softmax

  // phase 1a: n0 — u_hat tiles + scores (all operands from LDS)
#pragma unroll
  for (int c = 0; c < 8; ++c) {
    short8 av = {0, 0, 0, 0, 0, 0, 0, 0};
    short8 bv = {0, 0, 0, 0, 0, 0, 0, 0};
    if (q < 2) {
      av = *(const short8*)(&Wl[n0][c][b16][q * 8]);
      bv = *(const short8*)(&xl[b16][c * 16 + q * 8]);
    }
    f32x4 z = {0.f, 0.f, 0.f, 0.f};
    f32x4 d = __builtin_amdgcn_mfma_f32_16x16x32_bf16(av, bv, z, 0, 0, 0);
    t0[c] = d;
    float v = us0[0] * d[0] + us0[1] * d[1] + us0[2] * d[2] + us0[3] * d[3];
    v += __shfl_xor(v, 16);
    v += __shfl_xor(v, 32);
    if (l < 16) scl[n0][c][l] = COEF * v;
  }
  // phase 1b: n1
#pragma unroll
  for (int c = 0; c < 8; ++c) {
    short8 av = {0, 0, 0, 0, 0, 0, 0, 0};
    short8 bv = {0, 0, 0, 0, 0, 0, 0, 0};
    if (q < 2) {
      av = *(const short8*)(&Wl[n1][c][b16][q * 8]);
      bv = *(const short8*)(&xl[b16][c * 16 + q * 8]);
    }
    f32x4 z = {0.f, 0.f, 0.f, 0.f};
    f32x4 d = __builtin_amdgcn_mfma_f32_16x16x32_bf16(av, bv, z, 0, 0, 0);
    t1[c] = d;
    float v = us1[0] * d[0] + us1[1] * d[1] + us1[2] * d[2] + us1[3] * d[3];
    v += __shfl_xor(v, 16);
    v += __shfl_xor(v, 32);
    if (l < 16) scl[n1][c][l] = COEF * v;
  }
  __syncthreads();

  // phase 2: softmax over n + bias (threads < 128; thread owns (c,b) column)
  if (t < 128) {
    int c = t >> 4, b = t & 15;
    float v[NN];
    float m = -1e30f;
#pragma unroll
    for (int k = 0; k < NN; ++k) {
      v[k] = scl[k][c][b];
      m = fmaxf(m, v[k]);
    }
    float sum = 0.f;
#pragma unroll
    for (int k = 0; k < NN; ++k) {
      v[k] = expf(v[k] - m);
      sum += v[k];
    }
    float inv = 1.0f / sum;
#pragma unroll
    for (int k = 0; k < NN; ++k) {
      scl[k][c][b] = v[k] * inv + Bbias[k * NC + c0 + c];
    }
  }
  __syncthreads();

  // phase 3: weighted sum from register tiles
  f32x4 acc0 = {0.f, 0.f, 0.f, 0.f};
  f32x4 acc1 = {0.f, 0.f, 0.f, 0.f};
#pragma unroll
  for (int c = 0; c < 8; ++c) {
    float cf0 = scl[n0][c][b16];
    float cf1 = scl[n1][c][b16];
    acc0[0] = fmaf(cf0, t0[c][0], acc0[0]);
    acc0[1] = fmaf(cf0, t0[c][1], acc0[1]);
    acc0[2] = fmaf(cf0, t0[c][2], acc0[2]);
    acc0[3] = fmaf(cf0, t0[c][3], acc0[3]);
    acc1[0] = fmaf(cf1, t1[c][0], acc1[0]);
    acc1[1] = fmaf(cf1, t1[c][1], acc1[1]);
    acc1[2] = fmaf(cf1, t1[c][2], acc1[2]);
    acc1[3] = fmaf(cf1, t1[c][3], acc1[3]);
  }
  *(f32x4*)(part + ((size_t)((n0 * 8 + bt) * 128 + cc)) * 256 + b16 * 16 + q * 4) = acc0;
  *(f32x4*)(part + ((size_t)((n1 * 8 + bt) * 128 + cc)) * 256 + b16 * 16 + q * 4) = acc1;
}

// K4: reduce s partials over 128 cc + squash -> out[b][n][d].
// 128 blocks (n*8+bt) x 512 threads: thread (hh, t) sums cc in [hh*64,+64) of
// element t of the 256-float (b16,d) tile — fully coalesced 1KB/wave reads.
__global__ __launch_bounds__(512) void k_fin(const float* __restrict__ part,
                                             float* __restrict__ out) {
  __shared__ float red[256];
  int blk = blockIdx.x;  // n*8 + bt
  int n = blk >> 3, bt = blk & 7;
  int tid = threadIdx.x;
  int hh = tid >> 8, t = tid & 255;  // t = b16*16 + d
  const float* pp = part + ((size_t)blk * 128 + hh * 64) * 256 + t;
  float s = 0.f;
#pragma unroll 8
  for (int cc = 0; cc < 64; ++cc) {
    s += *pp;
    pp += 256;
  }
  if (hh) red[t] = s;
  __syncthreads();
  if (tid < 256) {
    float sv = s + red[t];
    float sq = sv * sv;
    sq += __shfl_xor(sq, 1);
    sq += __shfl_xor(sq, 2);
    sq += __shfl_xor(sq, 4);
    sq += __shfl_xor(sq, 8);  // reduce over d within each 16-lane (b16) group
    float norm = sqrtf(sq);
    float scale = (1.0f - expf(-norm)) / sqrtf(sq + 1e-8f);
    int b = bt * 16 + (t >> 4), d = t & 15;
    out[((size_t)b * NN + n) * ND + d] = sv * scale;
  }
}

extern "C" void kernel_launch(void* const* d_in, const int* in_sizes, int n_in,
                              void* d_out, int out_size, void* d_ws, size_t ws_size,
                              hipStream_t stream) {
  const float* x = (const float*)d_in[0];   // [128][1024][16]
  const float* W = (const float*)d_in[1];   // [1][16][1024][16][16]
  const float* Bb = (const float*)d_in[2];  // [16][1][1024]
  float* out = (float*)d_out;               // [128][16][16]
  float* ws = (float*)d_ws;

  // ws layout (float units): ~29.6 MB total
  ushort_t* xb = (ushort_t*)ws;              // 2,097,152 bf16 = 1,048,576 f
  ushort_t* Wb = (ushort_t*)(ws + 1048576);  // 4,194,304 bf16 = 2,097,152 f
  float* part = ws + 1048576 + 2097152;      // [16][8][128][256] = 4,194,304 f
  float* usum2 = part + 4194304;             // [2][16][128][16] = 65,536 f

  hipLaunchKernelGGL(k_prepx, dim3(1024), dim3(256), 0, stream, (const float4*)x, xb);
  hipLaunchKernelGGL(k_usum, dim3(256), dim3(1024), 0, stream, xb, W, Wb, usum2);
  hipLaunchKernelGGL(k_bc, dim3(1024), dim3(512), 0, stream, xb, Wb, usum2, Bb, part);
  hipLaunchKernelGGL(k_fin, dim3(128), dim3(512), 0, stream, part, out);
}

// Round 13
// 48.714 us; speedup vs baseline: 3.4273x; 1.0585x over previous
//
#include <hip/hip_runtime.h>
#include <math.h>

// DigitCaps2: B=128, C=1024 in_caps, I=16 in_dim, N=16 num_caps, D=16 dim_caps
#define NB 128
#define NC 1024
#define NN 16
#define ND 16
#define NI 16
#define COEF 0.25f

typedef __attribute__((ext_vector_type(8))) short short8;
typedef __attribute__((ext_vector_type(4))) float f32x4;
typedef unsigned short ushort_t;

__device__ __forceinline__ unsigned short f2bf(float f) {
  unsigned int u = __builtin_bit_cast(unsigned int, f);
  u += 0x7fffu + ((u >> 16) & 1u);
  return (unsigned short)(u >> 16);
}

// K1: convert x (262144 groups of 8) and W (524288 groups) to bf16.
__global__ __launch_bounds__(256) void k_prep(const float4* __restrict__ x,
                                              const float4* __restrict__ W,
                                              ushort_t* __restrict__ xb,
                                              ushort_t* __restrict__ Wb) {
  int id = blockIdx.x * 256 + threadIdx.x;
  const float4* src;
  ushort_t* dst;
  int k;
  if (id < 262144) { src = x; dst = xb; k = id; }
  else { src = W; dst = Wb; k = id - 262144; }
  float4 a = src[2 * k], b = src[2 * k + 1];
  short8 o;
  o[0] = (short)f2bf(a.x); o[1] = (short)f2bf(a.y);
  o[2] = (short)f2bf(a.z); o[3] = (short)f2bf(a.w);
  o[4] = (short)f2bf(b.x); o[5] = (short)f2bf(b.y);
  o[6] = (short)f2bf(b.z); o[7] = (short)f2bf(b.w);
  *(short8*)(dst + (size_t)k * 8) = o;
}

// K2: usum half-partials. bx = bt*32 + (n*2+h) so the 8 bt-blocks sharing a
// W half-slice land on the same XCD (bx mod 8 = (2n+h) mod 8) -> L2 reuse.
// 16 waves; wave w owns c in [h*512 + w*32, +32) as 4 independent 4-step chains.
// LDS-reduce 16 waves -> usum2[h][n][b][d].
__global__ __launch_bounds__(1024) void k_usum(const ushort_t* __restrict__ xb,
                                               const ushort_t* __restrict__ Wb,
                                               float* __restrict__ usum2) {
  __shared__ f32x4 red[16][64];  // 16 KB
  int bx = blockIdx.x;
  int bt = bx >> 5, g = bx & 31;
  int n = g >> 1, h = g & 1;
  int w = threadIdx.x >> 6, l = threadIdx.x & 63;
  int q = l >> 4, b16 = l & 15;
  int c0 = h * 512 + w * 32;
  f32x4 acc[4];
#pragma unroll
  for (int kk = 0; kk < 4; ++kk) acc[kk] = (f32x4){0.f, 0.f, 0.f, 0.f};
#pragma unroll
  for (int kk = 0; kk < 4; ++kk) {
    const ushort_t* ap =
        Wb + (((size_t)(n * NC + c0 + kk * 8 + (q >> 1)) * ND + b16) * NI) + (q & 1) * 8;
    const ushort_t* bp =
        xb + (size_t)(bt * 16 + b16) * (NC * NI) + (c0 + kk * 8 + (q >> 1)) * NI + (q & 1) * 8;
#pragma unroll
    for (int s = 0; s < 4; ++s) {
      short8 av = *(const short8*)ap;
      short8 bv = *(const short8*)bp;
      acc[kk] = __builtin_amdgcn_mfma_f32_16x16x32_bf16(av, bv, acc[kk], 0, 0, 0);
      ap += 2 * ND * NI;
      bp += 2 * NI;
    }
  }
  red[w][l] = (acc[0] + acc[1]) + (acc[2] + acc[3]);
  __syncthreads();
  if (threadIdx.x < 64) {
    f32x4 t = red[0][l];
#pragma unroll
    for (int k = 1; k < 16; ++k) t += red[k][l];
    *(f32x4*)(usum2 + (((size_t)h * NN + n) * NB + bt * 16 + b16) * ND + q * 4) = t;
  }
}

// K3: fused scores + softmax + weighted-sum. W staged via global_load_lds
// (async direct-to-LDS, no VGPR round-trip); x register-staged (padded tile).
// grid = 1024 blocks (bt = bx>>7, cc = bx&127); blocks sharing cc share an XCD.
// 512 threads = 8 waves; wave w handles n = w and n = w+8.
__global__ __launch_bounds__(512, 4) void k_bc(const ushort_t* __restrict__ xb,
                                               const ushort_t* __restrict__ Wb,
                                               const float* __restrict__ usum2,
                                               const float* __restrict__ Bbias,
                                               float* __restrict__ part) {
  __shared__ ushort_t Wl[NN][8][ND][NI];  // 64 KB, [n][c][d][i]
  __shared__ ushort_t xl[16][136];        // x tile [b][c*16+i], padded stride
  __shared__ float scl[NN][8][16];        // 8 KB, [n][c][b16]
  int bx = blockIdx.x;
  int bt = bx >> 7, cc = bx & 127;
  int t = threadIdx.x;
  int w = t >> 6, l = t & 63;
  int q = l >> 4, b16 = l & 15;
  int c0 = cc * 8;
  int n0 = w, n1 = w + 8;

  // ---- stage W slice via async global->LDS DMA: 64 segments of 1 KB ----
  // wave w copies segments {r*8+w}: LDS dest = Wflat + seg*512 shorts
  // (wave-uniform base; HW adds lane*16B), global src per-lane contiguous.
  {
    ushort_t* Wflat = &Wl[0][0][0][0];
    const ushort_t* Wsrc = Wb + (size_t)c0 * (ND * NI);
#pragma unroll
    for (int r = 0; r < 8; ++r) {
      int seg = r * 8 + w;                  // 0..63
      int nn = seg >> 2;                    // 4 KB (one n-chunk) = 4 segments
      int rem = ((seg & 3) << 9) + l * 8;   // shorts within the n-chunk
      const ushort_t* gp = Wsrc + (size_t)nn * (NC * ND * NI) + rem;
      ushort_t* lp = Wflat + seg * 512;
      __builtin_amdgcn_global_load_lds(
          (const __attribute__((address_space(1))) void*)gp,
          (__attribute__((address_space(3))) void*)lp, 16, 0, 0);
    }
    // stage x slice: 16 b x 8 c x 16 i (register path, padded LDS layout)
    if (t < 256) {
      int b = t >> 4, j = t & 15;  // j = c*2 + i-half
      int c = j >> 1, i8 = j & 1;
      *(short8*)(&xl[b][c * 16 + i8 * 8]) =
          *(const short8*)(xb + ((size_t)(bt * 16 + b) * NC + c0 + c) * NI + i8 * 8);
    }
  }

  // usum loads (overlap the staging DMA)
  const float* u0p = usum2 + ((size_t)n0 * NB + bt * 16 + b16) * ND + q * 4;
  f32x4 us0 = *(const f32x4*)u0p + *(const f32x4*)(u0p + (size_t)NN * NB * ND);
  const float* u1p = usum2 + ((size_t)n1 * NB + bt * 16 + b16) * ND + q * 4;
  f32x4 us1 = *(const f32x4*)u1p + *(const f32x4*)(u1p + (size_t)NN * NB * ND);

  __syncthreads();  // drains vmcnt (incl. global_load_lds) before LDS reads

  f32x4 t0[8], t1[8];  // u_hat d-tiles, kept in registers across softmax

  // phase 1a: n0 — u_hat tiles + scores (all operands from LDS)
#pragma unroll
  for (int c = 0; c < 8; ++c) {
    short8 av = {0, 0, 0, 0, 0, 0, 0, 0};
    short8 bv = {0, 0, 0, 0, 0, 0, 0, 0};
    if (q < 2) {
      av = *(const short8*)(&Wl[n0][c][b16][q * 8]);
      bv = *(const short8*)(&xl[b16][c * 16 + q * 8]);
    }
    f32x4 z = {0.f, 0.f, 0.f, 0.f};
    f32x4 d = __builtin_amdgcn_mfma_f32_16x16x32_bf16(av, bv, z, 0, 0, 0);
    t0[c] = d;
    float v = us0[0] * d[0] + us0[1] * d[1] + us0[2] * d[2] + us0[3] * d[3];
    v += __shfl_xor(v, 16);
    v += __shfl_xor(v, 32);
    if (l < 16) scl[n0][c][l] = COEF * v;
  }
  // phase 1b: n1
#pragma unroll
  for (int c = 0; c < 8; ++c) {
    short8 av = {0, 0, 0, 0, 0, 0, 0, 0};
    short8 bv = {0, 0, 0, 0, 0, 0, 0, 0};
    if (q < 2) {
      av = *(const short8*)(&Wl[n1][c][b16][q * 8]);
      bv = *(const short8*)(&xl[b16][c * 16 + q * 8]);
    }
    f32x4 z = {0.f, 0.f, 0.f, 0.f};
    f32x4 d = __builtin_amdgcn_mfma_f32_16x16x32_bf16(av, bv, z, 0, 0, 0);
    t1[c] = d;
    float v = us1[0] * d[0] + us1[1] * d[1] + us1[2] * d[2] + us1[3] * d[3];
    v += __shfl_xor(v, 16);
    v += __shfl_xor(v, 32);
    if (l < 16) scl[n1][c][l] = COEF * v;
  }
  __syncthreads();

  // phase 2: softmax over n + bias (threads < 128; thread owns (c,b) column)
  if (t < 128) {
    int c = t >> 4, b = t & 15;
    float v[NN];
    float m = -1e30f;
#pragma unroll
    for (int k = 0; k < NN; ++k) {
      v[k] = scl[k][c][b];
      m = fmaxf(m, v[k]);
    }
    float sum = 0.f;
#pragma unroll
    for (int k = 0; k < NN; ++k) {
      v[k] = expf(v[k] - m);
      sum += v[k];
    }
    float inv = 1.0f / sum;
#pragma unroll
    for (int k = 0; k < NN; ++k) {
      scl[k][c][b] = v[k] * inv + Bbias[k * NC + c0 + c];
    }
  }
  __syncthreads();

  // phase 3: weighted sum from register tiles
  f32x4 acc0 = {0.f, 0.f, 0.f, 0.f};
  f32x4 acc1 = {0.f, 0.f, 0.f, 0.f};
#pragma unroll
  for (int c = 0; c < 8; ++c) {
    float cf0 = scl[n0][c][b16];
    float cf1 = scl[n1][c][b16];
    acc0[0] = fmaf(cf0, t0[c][0], acc0[0]);
    acc0[1] = fmaf(cf0, t0[c][1], acc0[1]);
    acc0[2] = fmaf(cf0, t0[c][2], acc0[2]);
    acc0[3] = fmaf(cf0, t0[c][3], acc0[3]);
    acc1[0] = fmaf(cf1, t1[c][0], acc1[0]);
    acc1[1] = fmaf(cf1, t1[c][1], acc1[1]);
    acc1[2] = fmaf(cf1, t1[c][2], acc1[2]);
    acc1[3] = fmaf(cf1, t1[c][3], acc1[3]);
  }
  *(f32x4*)(part + ((size_t)((n0 * 8 + bt) * 128 + cc)) * 256 + b16 * 16 + q * 4) = acc0;
  *(f32x4*)(part + ((size_t)((n1 * 8 + bt) * 128 + cc)) * 256 + b16 * 16 + q * 4) = acc1;
}

// K4: reduce s partials over 128 cc (2-way split) + squash -> out[b][n][d].
__global__ __launch_bounds__(256) void k_fin(const float* __restrict__ part,
                                             float* __restrict__ out) {
  int id2 = blockIdx.x * 256 + threadIdx.x;  // 16384
  int h = id2 & 1;
  int id = id2 >> 1;  // 8192 = b*64 + n*4 + dq
  int dq = id & 3, n = (id >> 2) & 15, b = id >> 6;
  int bt = b >> 4, b16 = b & 15;
  f32x4 sv = {0.f, 0.f, 0.f, 0.f};
  const float* pp = part + ((size_t)((n * 8 + bt) * 128 + h * 64)) * 256 + b16 * 16 + dq * 4;
  for (int k = 0; k < 64; ++k) {
    sv += *(const f32x4*)pp;
    pp += 256;
  }
  // combine h halves (adjacent lanes)
  sv[0] += __shfl_xor(sv[0], 1);
  sv[1] += __shfl_xor(sv[1], 1);
  sv[2] += __shfl_xor(sv[2], 1);
  sv[3] += __shfl_xor(sv[3], 1);
  float sq = sv[0] * sv[0] + sv[1] * sv[1] + sv[2] * sv[2] + sv[3] * sv[3];
  sq += __shfl_xor(sq, 2);
  sq += __shfl_xor(sq, 4);
  float norm = sqrtf(sq);
  float scale = (1.0f - expf(-norm)) / sqrtf(sq + 1e-8f);
  if (h == 0) {
    f32x4 o = {sv[0] * scale, sv[1] * scale, sv[2] * scale, sv[3] * scale};
    *(f32x4*)(out + (size_t)id * 4) = o;
  }
}

extern "C" void kernel_launch(void* const* d_in, const int* in_sizes, int n_in,
                              void* d_out, int out_size, void* d_ws, size_t ws_size,
                              hipStream_t stream) {
  const float* x = (const float*)d_in[0];   // [128][1024][16]
  const float* W = (const float*)d_in[1];   // [1][16][1024][16][16]
  const float* Bb = (const float*)d_in[2];  // [16][1][1024]
  float* out = (float*)d_out;               // [128][16][16]
  float* ws = (float*)d_ws;

  // ws layout (float units): ~29.6 MB total
  ushort_t* xb = (ushort_t*)ws;              // 2,097,152 bf16 = 1,048,576 f
  ushort_t* Wb = (ushort_t*)(ws + 1048576);  // 4,194,304 bf16 = 2,097,152 f
  float* part = ws + 1048576 + 2097152;      // [16][8][128][256] = 4,194,304 f
  float* usum2 = part + 4194304;             // [2][16][128][16] = 65,536 f

  hipLaunchKernelGGL(k_prep, dim3(3072), dim3(256), 0, stream,
                     (const float4*)x, (const float4*)W, xb, Wb);
  hipLaunchKernelGGL(k_usum, dim3(256), dim3(1024), 0, stream, xb, Wb, usum2);
  hipLaunchKernelGGL(k_bc, dim3(1024), dim3(512), 0, stream, xb, Wb, usum2, Bb, part);
  hipLaunchKernelGGL(k_fin, dim3(64), dim3(256), 0, stream, part, out);
}

// Round 14
// 45.869 us; speedup vs baseline: 3.6399x; 1.0620x over previous
//
#include <hip/hip_runtime.h>
#include <math.h>

// DigitCaps2: B=128, C=1024 in_caps, I=16 in_dim, N=16 num_caps, D=16 dim_caps
#define NB 128
#define NC 1024
#define NN 16
#define ND 16
#define NI 16
#define COEF 0.25f

typedef __attribute__((ext_vector_type(8))) short short8;
typedef __attribute__((ext_vector_type(4))) short short4v;
typedef __attribute__((ext_vector_type(4))) float f32x4;
typedef unsigned short ushort_t;

__device__ __forceinline__ unsigned short f2bf(float f) {
  unsigned int u = __builtin_bit_cast(unsigned int, f);
  u += 0x7fffu + ((u >> 16) & 1u);
  return (unsigned short)(u >> 16);
}
__device__ __forceinline__ float bf2f(unsigned short u) {
  unsigned int v = ((unsigned int)u) << 16;
  return __builtin_bit_cast(float, v);
}

// K1: convert x (262144 groups of 8) and W (524288 groups) to bf16.
__global__ __launch_bounds__(256) void k_prep(const float4* __restrict__ x,
                                              const float4* __restrict__ W,
                                              ushort_t* __restrict__ xb,
                                              ushort_t* __restrict__ Wb) {
  int id = blockIdx.x * 256 + threadIdx.x;
  const float4* src;
  ushort_t* dst;
  int k;
  if (id < 262144) { src = x; dst = xb; k = id; }
  else { src = W; dst = Wb; k = id - 262144; }
  float4 a = src[2 * k], b = src[2 * k + 1];
  short8 o;
  o[0] = (short)f2bf(a.x); o[1] = (short)f2bf(a.y);
  o[2] = (short)f2bf(a.z); o[3] = (short)f2bf(a.w);
  o[4] = (short)f2bf(b.x); o[5] = (short)f2bf(b.y);
  o[6] = (short)f2bf(b.z); o[7] = (short)f2bf(b.w);
  *(short8*)(dst + (size_t)k * 8) = o;
}

// K2: usum half-partials. bx = bt*32 + (n*2+h) so the 8 bt-blocks sharing a
// W half-slice land on the same XCD -> L2 reuse. 16 waves; wave w owns
// c in [h*512 + w*32, +32) as 4 independent 4-step chains.
// LDS-reduce 16 waves -> usum2[h][n][b][d].
__global__ __launch_bounds__(1024) void k_usum(const ushort_t* __restrict__ xb,
                                               const ushort_t* __restrict__ Wb,
                                               float* __restrict__ usum2) {
  __shared__ f32x4 red[16][64];  // 16 KB
  int bx = blockIdx.x;
  int bt = bx >> 5, g = bx & 31;
  int n = g >> 1, h = g & 1;
  int w = threadIdx.x >> 6, l = threadIdx.x & 63;
  int q = l >> 4, b16 = l & 15;
  int c0 = h * 512 + w * 32;
  f32x4 acc[4];
#pragma unroll
  for (int kk = 0; kk < 4; ++kk) acc[kk] = (f32x4){0.f, 0.f, 0.f, 0.f};
#pragma unroll
  for (int kk = 0; kk < 4; ++kk) {
    const ushort_t* ap =
        Wb + (((size_t)(n * NC + c0 + kk * 8 + (q >> 1)) * ND + b16) * NI) + (q & 1) * 8;
    const ushort_t* bp =
        xb + (size_t)(bt * 16 + b16) * (NC * NI) + (c0 + kk * 8 + (q >> 1)) * NI + (q & 1) * 8;
#pragma unroll
    for (int s = 0; s < 4; ++s) {
      short8 av = *(const short8*)ap;
      short8 bv = *(const short8*)bp;
      acc[kk] = __builtin_amdgcn_mfma_f32_16x16x32_bf16(av, bv, acc[kk], 0, 0, 0);
      ap += 2 * ND * NI;
      bp += 2 * NI;
    }
  }
  red[w][l] = (acc[0] + acc[1]) + (acc[2] + acc[3]);
  __syncthreads();
  if (threadIdx.x < 64) {
    f32x4 t = red[0][l];
#pragma unroll
    for (int k = 1; k < 16; ++k) t += red[k][l];
    *(f32x4*)(usum2 + (((size_t)h * NN + n) * NB + bt * 16 + b16) * ND + q * 4) = t;
  }
}

// K3: fused scores + softmax + weighted-sum. LDS-staged W/x, register u_hat
// tiles. grid = 1024 blocks (bt = bx>>7, cc = bx&127); blocks sharing cc share
// an XCD. 512 threads = 8 waves; wave w handles n = w and n = w+8.
// s-partials written as BF16 (halves part traffic; err ~2e-4 after 128-sum).
__global__ __launch_bounds__(512, 4) void k_bc(const ushort_t* __restrict__ xb,
                                               const ushort_t* __restrict__ Wb,
                                               const float* __restrict__ usum2,
                                               const float* __restrict__ Bbias,
                                               ushort_t* __restrict__ part) {
  __shared__ ushort_t Wl[NN][8][ND][NI];  // 64 KB, [n][c][d][i]
  __shared__ ushort_t xl[16][136];        // x tile [b][c*16+i], padded stride
  __shared__ float scl[NN][8][16];        // 8 KB, [n][c][b16]
  int bx = blockIdx.x;
  int bt = bx >> 7, cc = bx & 127;
  int t = threadIdx.x;
  int w = t >> 6, l = t & 63;
  int q = l >> 4, b16 = l & 15;
  int c0 = cc * 8;
  int n0 = w, n1 = w + 8;

  // usum loads issued first so they overlap the staging burst below
  const float* u0p = usum2 + ((size_t)n0 * NB + bt * 16 + b16) * ND + q * 4;
  f32x4 us0 = *(const f32x4*)u0p + *(const f32x4*)(u0p + (size_t)NN * NB * ND);
  const float* u1p = usum2 + ((size_t)n1 * NB + bt * 16 + b16) * ND + q * 4;
  f32x4 us1 = *(const f32x4*)u1p + *(const f32x4*)(u1p + (size_t)NN * NB * ND);

  // ---- stage W slice: 16 n x (8 c x 256) shorts = 4096 short8 groups ----
  {
    ushort_t* Wflat = &Wl[0][0][0][0];
    const ushort_t* Wsrc = Wb + (size_t)c0 * (ND * NI);
#pragma unroll
    for (int r = 0; r < 8; ++r) {
      int g = r * 512 + t;            // 0..4095
      int n = g >> 8, rem = g & 255;  // 256 short8 per n-chunk (contiguous)
      *(short8*)(Wflat + n * 2048 + rem * 8) =
          *(const short8*)(Wsrc + (size_t)n * (NC * ND * NI) + rem * 8);
    }
    // stage x slice: 16 b x 8 c x 16 i
    if (t < 256) {
      int b = t >> 4, j = t & 15;  // j = c*2 + i-half
      int c = j >> 1, i8 = j & 1;
      *(short8*)(&xl[b][c * 16 + i8 * 8]) =
          *(const short8*)(xb + ((size_t)(bt * 16 + b) * NC + c0 + c) * NI + i8 * 8);
    }
  }
  __syncthreads();

  f32x4 t0[8], t1[8];  // u_hat d-tiles, kept in registers across softmax

  // phase 1a: n0 — u_hat tiles + scores (all operands from LDS)
#pragma unroll
  for (int c = 0; c < 8; ++c) {
    short8 av = {0, 0, 0, 0, 0, 0, 0, 0};
    short8 bv = {0, 0, 0, 0, 0, 0, 0, 0};
    if (q < 2) {
      av = *(const short8*)(&Wl[n0][c][b16][q * 8]);
      bv = *(const short8*)(&xl[b16][c * 16 + q * 8]);
    }
    f32x4 z = {0.f, 0.f, 0.f, 0.f};
    f32x4 d = __builtin_amdgcn_mfma_f32_16x16x32_bf16(av, bv, z, 0, 0, 0);
    t0[c] = d;
    float v = us0[0] * d[0] + us0[1] * d[1] + us0[2] * d[2] + us0[3] * d[3];
    v += __shfl_xor(v, 16);
    v += __shfl_xor(v, 32);
    if (l < 16) scl[n0][c][l] = COEF * v;
  }
  // phase 1b: n1
#pragma unroll
  for (int c = 0; c < 8; ++c) {
    short8 av = {0, 0, 0, 0, 0, 0, 0, 0};
    short8 bv = {0, 0, 0, 0, 0, 0, 0, 0};
    if (q < 2) {
      av = *(const short8*)(&Wl[n1][c][b16][q * 8]);
      bv = *(const short8*)(&xl[b16][c * 16 + q * 8]);
    }
    f32x4 z = {0.f, 0.f, 0.f, 0.f};
    f32x4 d = __builtin_amdgcn_mfma_f32_16x16x32_bf16(av, bv, z, 0, 0, 0);
    t1[c] = d;
    float v = us1[0] * d[0] + us1[1] * d[1] + us1[2] * d[2] + us1[3] * d[3];
    v += __shfl_xor(v, 16);
    v += __shfl_xor(v, 32);
    if (l < 16) scl[n1][c][l] = COEF * v;
  }
  __syncthreads();

  // phase 2: softmax over n + bias (threads < 128; thread owns (c,b) column)
  if (t < 128) {
    int c = t >> 4, b = t & 15;
    float v[NN];
    float m = -1e30f;
#pragma unroll
    for (int k = 0; k < NN; ++k) {
      v[k] = scl[k][c][b];
      m = fmaxf(m, v[k]);
    }
    float sum = 0.f;
#pragma unroll
    for (int k = 0; k < NN; ++k) {
      v[k] = expf(v[k] - m);
      sum += v[k];
    }
    float inv = 1.0f / sum;
#pragma unroll
    for (int k = 0; k < NN; ++k) {
      scl[k][c][b] = v[k] * inv + Bbias[k * NC + c0 + c];
    }
  }
  __syncthreads();

  // phase 3: weighted sum from register tiles; store bf16 partials
  f32x4 acc0 = {0.f, 0.f, 0.f, 0.f};
  f32x4 acc1 = {0.f, 0.f, 0.f, 0.f};
#pragma unroll
  for (int c = 0; c < 8; ++c) {
    float cf0 = scl[n0][c][b16];
    float cf1 = scl[n1][c][b16];
    acc0[0] = fmaf(cf0, t0[c][0], acc0[0]);
    acc0[1] = fmaf(cf0, t0[c][1], acc0[1]);
    acc0[2] = fmaf(cf0, t0[c][2], acc0[2]);
    acc0[3] = fmaf(cf0, t0[c][3], acc0[3]);
    acc1[0] = fmaf(cf1, t1[c][0], acc1[0]);
    acc1[1] = fmaf(cf1, t1[c][1], acc1[1]);
    acc1[2] = fmaf(cf1, t1[c][2], acc1[2]);
    acc1[3] = fmaf(cf1, t1[c][3], acc1[3]);
  }
  short4v p0 = {(short)f2bf(acc0[0]), (short)f2bf(acc0[1]),
                (short)f2bf(acc0[2]), (short)f2bf(acc0[3])};
  short4v p1 = {(short)f2bf(acc1[0]), (short)f2bf(acc1[1]),
                (short)f2bf(acc1[2]), (short)f2bf(acc1[3])};
  *(short4v*)(part + ((size_t)((n0 * 8 + bt) * 128 + cc)) * 256 + b16 * 16 + q * 4) = p0;
  *(short4v*)(part + ((size_t)((n1 * 8 + bt) * 128 + cc)) * 256 + b16 * 16 + q * 4) = p1;
}

// K4: reduce bf16 s partials over 128 cc (4-way split) + squash -> out[b][n][d].
// 128 blocks x 256 threads; lane group of 4 (h) sums 32 cc each, shfl-combine.
__global__ __launch_bounds__(256) void k_fin(const ushort_t* __restrict__ part,
                                             float* __restrict__ out) {
  int id2 = blockIdx.x * 256 + threadIdx.x;  // 32768
  int h = id2 & 3;
  int id = id2 >> 2;  // 8192 = b*64 + n*4 + dq
  int dq = id & 3, n = (id >> 2) & 15, b = id >> 6;
  int bt = b >> 4, b16 = b & 15;
  f32x4 sv = {0.f, 0.f, 0.f, 0.f};
  const ushort_t* pp =
      part + ((size_t)((n * 8 + bt) * 128 + h * 32)) * 256 + b16 * 16 + dq * 4;
#pragma unroll 8
  for (int k = 0; k < 32; ++k) {
    short4v p = *(const short4v*)pp;
    sv[0] += bf2f((unsigned short)p[0]);
    sv[1] += bf2f((unsigned short)p[1]);
    sv[2] += bf2f((unsigned short)p[2]);
    sv[3] += bf2f((unsigned short)p[3]);
    pp += 256;
  }
  // combine the 4 h-lanes (adjacent)
#pragma unroll
  for (int j = 0; j < 4; ++j) {
    sv[j] += __shfl_xor(sv[j], 1);
    sv[j] += __shfl_xor(sv[j], 2);
  }
  float sq = sv[0] * sv[0] + sv[1] * sv[1] + sv[2] * sv[2] + sv[3] * sv[3];
  sq += __shfl_xor(sq, 4);
  sq += __shfl_xor(sq, 8);  // sum over dq groups -> full ||s||^2
  float norm = sqrtf(sq);
  float scale = (1.0f - expf(-norm)) / sqrtf(sq + 1e-8f);
  if (h == 0) {
    f32x4 o = {sv[0] * scale, sv[1] * scale, sv[2] * scale, sv[3] * scale};
    *(f32x4*)(out + (size_t)id * 4) = o;
  }
}

extern "C" void kernel_launch(void* const* d_in, const int* in_sizes, int n_in,
                              void* d_out, int out_size, void* d_ws, size_t ws_size,
                              hipStream_t stream) {
  const float* x = (const float*)d_in[0];   // [128][1024][16]
  const float* W = (const float*)d_in[1];   // [1][16][1024][16][16]
  const float* Bb = (const float*)d_in[2];  // [16][1][1024]
  float* out = (float*)d_out;               // [128][16][16]
  float* ws = (float*)d_ws;

  // ws layout (float units): ~21.3 MB total
  ushort_t* xb = (ushort_t*)ws;              // 2,097,152 bf16 = 1,048,576 f
  ushort_t* Wb = (ushort_t*)(ws + 1048576);  // 4,194,304 bf16 = 2,097,152 f
  ushort_t* part = (ushort_t*)(ws + 1048576 + 2097152);  // bf16 [16][8][128][256] = 2,097,152 f
  float* usum2 = ws + 1048576 + 2097152 + 2097152;       // [2][16][128][16] = 65,536 f

  hipLaunchKernelGGL(k_prep, dim3(3072), dim3(256), 0, stream,
                     (const float4*)x, (const float4*)W, xb, Wb);
  hipLaunchKernelGGL(k_usum, dim3(256), dim3(1024), 0, stream, xb, Wb, usum2);
  hipLaunchKernelGGL(k_bc, dim3(1024), dim3(512), 0, stream, xb, Wb, usum2, Bb, part);
  hipLaunchKernelGGL(k_fin, dim3(128), dim3(256), 0, stream, part, out);
}